// Round 10
// baseline (393.787 us; speedup 1.0000x reference)
//
#include <hip/hip_runtime.h>
#include <hip/hip_bf16.h>
#include <stdint.h>

#define E_    8
#define CAP_  2048
#define D_    1024
#define H_    4096

typedef unsigned short u16;
typedef __attribute__((ext_vector_type(8))) short bf16x8;   // 8 bf16 in 4 VGPRs
typedef __attribute__((ext_vector_type(4))) float f32x4;

__device__ __forceinline__ u16 f2bf(float f) {
    union { float f; unsigned int u; } v; v.f = f;
    unsigned int u = v.u;
    unsigned int r = (u + 0x7fffu + ((u >> 16) & 1u)) >> 16;   // round-nearest-even
    return (u16)r;
}

__device__ __forceinline__ void gload_lds16(const void* g, void* l) {
    __builtin_amdgcn_global_load_lds(
        (const __attribute__((address_space(1))) unsigned int*)g,
        (__attribute__((address_space(3))) unsigned int*)l,
        16, 0, 0);
}

// ---------------- fp32 -> bf16 elementwise convert (vectorized) ----------------
__global__ void cvt_f32_bf16(const float* __restrict__ in, u16* __restrict__ out, int n4) {
    int i = blockIdx.x * blockDim.x + threadIdx.x;
    if (i >= n4) return;
    const float4 v = ((const float4*)in)[i];
    ushort4 o;
    o.x = f2bf(v.x); o.y = f2bf(v.y); o.z = f2bf(v.z); o.w = f2bf(v.w);
    ((ushort4*)out)[i] = o;
}

// ---------------- W2 [E][H][D] fp32 -> W2T [E][D][H] bf16 (64x64 tiles) ----------------
__global__ void transpose_cvt(const float* __restrict__ in, u16* __restrict__ out) {
    __shared__ float t[64][69];
    const int e  = blockIdx.z;
    const int h0 = blockIdx.y * 64;
    const int d0 = blockIdx.x * 64;
    const float* I = in + (size_t)e * H_ * D_;
    u16* O = out + (size_t)e * D_ * H_;
    const int tid = threadIdx.x;
    const int r  = tid >> 4;          // 0..15
    const int c  = (tid & 15) * 4;    // 0..60
    #pragma unroll
    for (int s = 0; s < 4; ++s) {
        const int h = r + s * 16;
        const float4 v = *(const float4*)&I[(size_t)(h0 + h) * D_ + d0 + c];
        t[h][c] = v.x; t[h][c + 1] = v.y; t[h][c + 2] = v.z; t[h][c + 3] = v.w;
    }
    __syncthreads();
    #pragma unroll
    for (int s = 0; s < 4; ++s) {
        const int d = r + s * 16;
        ushort4 o;
        o.x = f2bf(t[c + 0][d]); o.y = f2bf(t[c + 1][d]);
        o.z = f2bf(t[c + 2][d]); o.w = f2bf(t[c + 3][d]);
        *(ushort4*)&O[(size_t)(d0 + d) * H_ + h0 + c] = o;
    }
}

// ---------------- 256x128xBK32 bf16 B^T GEMM, 2 blocks/CU ----------------
// C[M,N] = A[M,K]*B[N,K]^T + bias; EPI 0: +relu bf16 out; EPI 1: fp32 out.
// 8 waves as 4M x 2N, per-wave 64x64 output (acc = 64 VGPR -> total ~115 ->
// __launch_bounds__(512,4) -> 4 waves/SIMD -> TWO blocks/CU). LDS 64 KiB:
// main loop uses 2 x 24 KiB double buffer [A 256x32 | B 128x32]; epilogue
// re-stages C through the same 64 KiB. Cross-BLOCK overlap hides the
// vmcnt/barrier drain that serialized MFMA and LDS pipes at 1 block/CU
// (r5-r9: wall == MFMA + LDS + OH summed).
// Swizzle (BK=32): physical granule = logical k-granule fq ^ ((row>>1)&3);
// staging keeps LDS linear + pre-swizzled global source (involution,
// kel = ((tid&3)^((tid>>3)&3))*8). 2 lanes/bank-slot max per 16-lane group.
template<int EPI>
__global__ __launch_bounds__(512, 4) void gemm128(
    const u16* __restrict__ A, const u16* __restrict__ B,
    const float* __restrict__ bias, void* __restrict__ Cv,
    int M, int N, int K, int TM, int TN,
    size_t sA, size_t sB, size_t sBias, size_t sC)
{
    __shared__ __align__(16) u16 lds[32768];   // 64 KiB

    // XCD-aware bijective swizzle (gridDim.x % 8 == 0 by construction)
    const int nwg = gridDim.x;
    const int cpx = nwg >> 3;
    const int bid = blockIdx.x;
    const int wg  = (bid & 7) * cpx + (bid >> 3);
    const int tpe = TM * TN;
    const int e   = wg / tpe;
    const int rem = wg - e * tpe;
    const int tm  = rem / TN;        // tn inner: consecutive wg share A-panel
    const int tn  = rem - tm * TN;
    const int row0 = tm << 8;        // 256-row tiles
    const int col0 = tn << 7;        // 128-col tiles

    const u16* Ae = A + (size_t)e * sA;
    const u16* Be = B + (size_t)e * sB;

    const int tid  = threadIdx.x;
    const int lane = tid & 63;
    const int w    = tid >> 6;       // 8 waves
    const int wr   = w >> 1;         // 0..3  (M)
    const int wc   = w & 1;          // 0..1  (N)
    const int fr   = lane & 15;
    const int fq   = lane >> 4;      // k-granule 0..3 (8 bf16 each)
    // swizzled per-lane read offset within a [rows][32]-bf16 region (bytes)
    const int L    = fr * 64 + ((fq ^ ((fr >> 1) & 3)) << 4);
    const int NT   = K >> 5;

    // staging: thread stages A rows (tid>>2, +128) and B row (tid>>2), at
    // logical k-elems kel..kel+7; LDS dest is linear 16B chunks by tid.
    const int arow = tid >> 2;                                  // 0..127
    const int kel  = (((tid & 3) ^ ((tid >> 3) & 3)) << 3);     // 0,8,16,24
    const u16* pA0 = Ae + (size_t)(row0 + arow) * K + kel;
    const u16* pA1 = Ae + (size_t)(row0 + 128 + arow) * K + kel;
    const u16* pB0 = Be + (size_t)(col0 + arow) * K + kel;

    auto stage = [&](int buf, bool pred) {
        u16* base = lds + buf * 12288;
        if (pred) {
            gload_lds16(pA0, base + tid * 8);
            gload_lds16(pA1, base + 4096 + tid * 8);
            gload_lds16(pB0, base + 8192 + tid * 8);
        }
        pA0 += 32; pA1 += 32; pB0 += 32;
    };

    f32x4 acc[4][4] = {};

    stage(0, true);
    asm volatile("s_waitcnt vmcnt(0)");
    __builtin_amdgcn_s_barrier();

    for (int t = 0; t < NT; ++t) {
        const int db = t & 1;
        const char* Ab = (const char*)lds + db * 24576;
        const char* Bb = Ab + 16384;

        stage(db ^ 1, t + 1 < NT);       // lead-1, into the other buffer

        bf16x8 b[4], a[4];
        #pragma unroll
        for (int n = 0; n < 4; ++n)
            b[n] = *(const bf16x8*)(Bb + wc * 4096 + n * 1024 + L);
        #pragma unroll
        for (int m = 0; m < 4; ++m)
            a[m] = *(const bf16x8*)(Ab + wr * 4096 + m * 1024 + L);

        __builtin_amdgcn_s_setprio(1);
        #pragma unroll
        for (int m = 0; m < 4; ++m)
            #pragma unroll
            for (int n = 0; n < 4; ++n)
                acc[m][n] = __builtin_amdgcn_mfma_f32_16x16x32_bf16(
                    a[m], b[n], acc[m][n], 0, 0, 0);
        __builtin_amdgcn_s_setprio(0);

        asm volatile("s_waitcnt vmcnt(0)");   // staged tile t+1 complete
        __builtin_amdgcn_s_barrier();
    }

    // ---------------- coalesced epilogue via LDS re-staging ----------------
    // C/D frag layout: col = lane&15, row = (lane>>4)*4 + reg
    const float* be = bias + (size_t)e * sBias;
    if (EPI == 0) {
        // bf16 out: whole 256x128 tile as u16 -> 64 KiB, one pass
        u16* cl = lds;
        #pragma unroll
        for (int n = 0; n < 4; ++n) {
            const int ccol = wc * 64 + n * 16 + fr;
            const float bv = be[col0 + ccol];
            #pragma unroll
            for (int m = 0; m < 4; ++m) {
                const int crow = wr * 64 + m * 16 + fq * 4;
                #pragma unroll
                for (int i = 0; i < 4; ++i) {
                    float v = acc[m][n][i] + bv;
                    v = v > 0.f ? v : 0.f;
                    cl[(crow + i) * 128 + ccol] = f2bf(v);
                }
            }
        }
        __builtin_amdgcn_s_barrier();
        u16* Ce = (u16*)Cv + (size_t)e * sC;
        const int rr = tid >> 4;           // 0..31
        const int cc = (tid & 15) * 8;     // u16 col, 16B granular
        #pragma unroll
        for (int s = 0; s < 8; ++s) {
            const int row = s * 32 + rr;
            const float4 v = *(const float4*)&cl[row * 128 + cc];
            *(float4*)&Ce[(size_t)(row0 + row) * N + col0 + cc] = v;
        }
    } else {
        // fp32 out: two passes of 128 rows (64 KiB each); pass p handled by
        // waves wr in {2p, 2p+1}
        float* cf = (float*)lds;
        float* Ce = (float*)Cv + (size_t)e * sC;
        #pragma unroll
        for (int p = 0; p < 2; ++p) {
            __builtin_amdgcn_s_barrier();
            if ((wr >> 1) == p) {
                #pragma unroll
                for (int n = 0; n < 4; ++n) {
                    const int ccol = wc * 64 + n * 16 + fr;
                    const float bv = be[col0 + ccol];
                    #pragma unroll
                    for (int m = 0; m < 4; ++m) {
                        const int lrow = (wr & 1) * 64 + m * 16 + fq * 4;
                        #pragma unroll
                        for (int i = 0; i < 4; ++i)
                            cf[(lrow + i) * 128 + ccol] = acc[m][n][i] + bv;
                    }
                }
            }
            __builtin_amdgcn_s_barrier();
            const int lr = tid >> 5;          // 0..15
            const int cc = (tid & 31) * 4;    // f32 col, 16B granular
            #pragma unroll
            for (int s = 0; s < 8; ++s) {
                const int lrow = s * 16 + lr;
                const int grow = row0 + p * 128 + lrow;
                const float4 v = *(const float4*)&cf[lrow * 128 + cc];
                *(float4*)&Ce[(size_t)grow * N + col0 + cc] = v;
            }
        }
    }
}

extern "C" void kernel_launch(void* const* d_in, const int* in_sizes, int n_in,
                              void* d_out, int out_size, void* d_ws, size_t ws_size,
                              hipStream_t stream) {
    (void)in_sizes; (void)n_in; (void)out_size; (void)ws_size;
    const float* x     = (const float*)d_in[0];
    const float* fc1_w = (const float*)d_in[1];
    const float* fc1_b = (const float*)d_in[2];
    const float* fc2_w = (const float*)d_in[3];
    const float* fc2_b = (const float*)d_in[4];
    float* out = (float*)d_out;

    // workspace layout (ushorts): xbf | w1bf | w2t | y1  => 288 MiB total
    u16* xbf  = (u16*)d_ws;                                 // E*CAP*D
    u16* w1bf = xbf  + (size_t)E_ * CAP_ * D_;              // E*H*D
    u16* w2t  = w1bf + (size_t)E_ * H_ * D_;                // E*D*H (transposed)
    u16* y1   = w2t  + (size_t)E_ * D_ * H_;                // E*CAP*H

    {   // x -> bf16
        int n4 = E_ * CAP_ * D_ / 4;
        cvt_f32_bf16<<<n4 / 256, 256, 0, stream>>>(x, xbf, n4);
    }
    {   // W1 -> bf16
        int n4 = E_ * H_ * D_ / 4;
        cvt_f32_bf16<<<n4 / 256, 256, 0, stream>>>(fc1_w, w1bf, n4);
    }
    // W2 -> bf16 transposed [E][D][H]
    transpose_cvt<<<dim3(D_ / 64, H_ / 64, E_), 256, 0, stream>>>(fc2_w, w2t);

    // GEMM1: y1[e] = relu(x[e] @ W1[e]^T + b1)   (M=CAP, N=H, K=D)
    gemm128<0><<<dim3(E_ * (CAP_ / 256) * (H_ / 128)), 512, 0, stream>>>(
        xbf, w1bf, fc1_b, y1, CAP_, H_, D_, CAP_ / 256, H_ / 128,
        (size_t)CAP_ * D_, (size_t)H_ * D_, (size_t)H_, (size_t)CAP_ * H_);

    // GEMM2: out[e] = y1[e] @ W2T[e]^T + b2   (M=CAP, N=D, K=H)
    gemm128<1><<<dim3(E_ * (CAP_ / 256) * (D_ / 128)), 512, 0, stream>>>(
        y1, w2t, fc2_b, out, CAP_, D_, H_, CAP_ / 256, D_ / 128,
        (size_t)CAP_ * H_, (size_t)D_ * H_, (size_t)D_, (size_t)CAP_ * D_);
}

// Round 11
// 354.057 us; speedup vs baseline: 1.1122x; 1.1122x over previous
//
#include <hip/hip_runtime.h>
#include <hip/hip_bf16.h>
#include <stdint.h>

#define E_    8
#define CAP_  2048
#define D_    1024
#define H_    4096

typedef unsigned short u16;
typedef __attribute__((ext_vector_type(8))) short bf16x8;   // 8 bf16 in 4 VGPRs
typedef __attribute__((ext_vector_type(4))) float f32x4;

__device__ __forceinline__ u16 f2bf(float f) {
    union { float f; unsigned int u; } v; v.f = f;
    unsigned int u = v.u;
    unsigned int r = (u + 0x7fffu + ((u >> 16) & 1u)) >> 16;   // round-nearest-even
    return (u16)r;
}

__device__ __forceinline__ void gload_lds16(const void* g, void* l) {
    __builtin_amdgcn_global_load_lds(
        (const __attribute__((address_space(1))) unsigned int*)g,
        (__attribute__((address_space(3))) unsigned int*)l,
        16, 0, 0);
}

// ---------------- fp32 -> bf16 elementwise convert (vectorized) ----------------
__global__ void cvt_f32_bf16(const float* __restrict__ in, u16* __restrict__ out, int n4) {
    int i = blockIdx.x * blockDim.x + threadIdx.x;
    if (i >= n4) return;
    const float4 v = ((const float4*)in)[i];
    ushort4 o;
    o.x = f2bf(v.x); o.y = f2bf(v.y); o.z = f2bf(v.z); o.w = f2bf(v.w);
    ((ushort4*)out)[i] = o;
}

// ---------------- W2 [E][H][D] fp32 -> W2T [E][D][H] bf16 (64x64 tiles) ----------------
__global__ void transpose_cvt(const float* __restrict__ in, u16* __restrict__ out) {
    __shared__ float t[64][69];
    const int e  = blockIdx.z;
    const int h0 = blockIdx.y * 64;
    const int d0 = blockIdx.x * 64;
    const float* I = in + (size_t)e * H_ * D_;
    u16* O = out + (size_t)e * D_ * H_;
    const int tid = threadIdx.x;
    const int r  = tid >> 4;          // 0..15
    const int c  = (tid & 15) * 4;    // 0..60
    #pragma unroll
    for (int s = 0; s < 4; ++s) {
        const int h = r + s * 16;
        const float4 v = *(const float4*)&I[(size_t)(h0 + h) * D_ + d0 + c];
        t[h][c] = v.x; t[h][c + 1] = v.y; t[h][c + 2] = v.z; t[h][c + 3] = v.w;
    }
    __syncthreads();
    #pragma unroll
    for (int s = 0; s < 4; ++s) {
        const int d = r + s * 16;
        ushort4 o;
        o.x = f2bf(t[c + 0][d]); o.y = f2bf(t[c + 1][d]);
        o.z = f2bf(t[c + 2][d]); o.w = f2bf(t[c + 3][d]);
        *(ushort4*)&O[(size_t)(d0 + d) * H_ + h0 + c] = o;
    }
}

// ---------------- 256x256x64 8-phase bf16 B^T GEMM (m201 skeleton) ----------------
// C[M,N] = A[M,K]*B[N,K]^T + bias; EPI 0: +relu bf16 out; EPI 1: fp32 out.
// 8 waves (2M x 4N), per-wave 128x64. LDS 128KiB [db][A/B][half][128*64];
// 3-bit XOR swizzle (0 main-loop conflicts, verified r3). Phase skeleton per
// m201: {ds_reads; stage; SB0; s_barrier; lgkmcnt(0); SB0; MFMA x16; SB0;
// [vmcnt] ; s_barrier}. The sched_barrier(0) pins stop hipcc from sinking the
// ds_reads past the raw s_barrier (rule-18 class) - reads must be IN FLIGHT
// when the wave crosses the barrier so the FIFO drain staggers waves' MFMA
// starts and LDS drain overlaps MFMA execution (the m201 overlap mechanism).
// Staging: A(t+1) at p0/p1, B(t+2) at p2/p3; counted vmcnt(4) once per tile.
template<int EPI>
__global__ __launch_bounds__(512, 2) void gemm256(
    const u16* __restrict__ A, const u16* __restrict__ B,
    const float* __restrict__ bias, void* __restrict__ Cv,
    int M, int N, int K, int TM, int TN,
    size_t sA, size_t sB, size_t sBias, size_t sC)
{
    __shared__ __align__(16) u16 lds[2][2][2][128 * 64];   // 128 KiB

    // XCD-aware bijective swizzle (gridDim.x % 8 == 0 by construction)
    const int nwg = gridDim.x;
    const int cpx = nwg >> 3;
    const int bid = blockIdx.x;
    const int wg  = (bid & 7) * cpx + (bid >> 3);
    const int tpe = TM * TN;
    const int e   = wg / tpe;
    const int rem = wg - e * tpe;
    const int tn  = rem / TM;        // tm inner: consecutive wg share B-panel
    const int tm  = rem - tn * TM;
    const int row0 = tm << 8;
    const int col0 = tn << 8;

    const u16* Ae = A + (size_t)e * sA;
    const u16* Be = B + (size_t)e * sB;

    const int tid  = threadIdx.x;
    const int lane = tid & 63;
    const int w    = tid >> 6;       // 8 waves
    const int wr   = w >> 2;         // 0..1  (M)
    const int wc   = w & 3;          // 0..3  (N)
    const int wcH  = wc >> 1;        // B half
    const int wcL  = wc & 1;
    const int fr   = lane & 15;
    const int fq   = lane >> 4;
    // swizzled per-lane read offsets within a [128][64]-bf16 half (bytes)
    const int cx   = (fq ^ (fr & 7)) << 4;
    const int lo0  = fr * 128 + cx;          // kk = 0
    const int lo1  = fr * 128 + (cx ^ 64);   // kk = 1
    // staging source pre-swizzle (involution)
    const int sl   = lane ^ ((lane >> 3) & 7);
    const int NT   = K >> 6;

    // per-thread staging pointers, advanced +64 elems (128B) per staged half
    const int srow = (w << 4) + (sl >> 3);
    const int scol = (sl & 7) << 3;
    const u16* pA[2][2];
    const u16* pB[2][2];
    #pragma unroll
    for (int l = 0; l < 2; ++l)
        #pragma unroll
        for (int hf = 0; hf < 2; ++hf) {
            pA[l][hf] = Ae + (size_t)(row0 + hf * 128 + srow + l * 8) * K + scol;
            pB[l][hf] = Be + (size_t)(col0 + hf * 128 + srow + l * 8) * K + scol;
        }

    // stage ONE 128x64 half-tile (2 gload_lds per thread)
    auto stA = [&](int buf, int hf, bool pred) {
        #pragma unroll
        for (int l = 0; l < 2; ++l) {
            if (pred) gload_lds16(pA[l][hf], &lds[buf][0][hf][(w * 2 + l) * 512]);
            pA[l][hf] += 64;
        }
    };
    auto stB = [&](int buf, int hf, bool pred) {
        #pragma unroll
        for (int l = 0; l < 2; ++l) {
            if (pred) gload_lds16(pB[l][hf], &lds[buf][1][hf][(w * 2 + l) * 512]);
            pB[l][hf] += 64;
        }
    };

    f32x4 acc[8][4] = {};
    bf16x8 b[4][2], aE[2][2], aO[2][2];

    auto rdA = [&](bf16x8 (&dst)[2][2], const char* Ah, int p) {
        dst[0][0] = *(const bf16x8*)(Ah + (2 * p + 0) * 2048 + lo0);
        dst[0][1] = *(const bf16x8*)(Ah + (2 * p + 0) * 2048 + lo1);
        dst[1][0] = *(const bf16x8*)(Ah + (2 * p + 1) * 2048 + lo0);
        dst[1][1] = *(const bf16x8*)(Ah + (2 * p + 1) * 2048 + lo1);
    };
    auto rdB = [&](const char* Bq) {
        #pragma unroll
        for (int n = 0; n < 4; ++n) {
            b[n][0] = *(const bf16x8*)(Bq + n * 2048 + lo0);
            b[n][1] = *(const bf16x8*)(Bq + n * 2048 + lo1);
        }
    };
    auto mf = [&](bf16x8 (&a)[2][2], int p) {
        __builtin_amdgcn_s_setprio(1);
        #pragma unroll
        for (int kk = 0; kk < 2; ++kk)
            #pragma unroll
            for (int mm = 0; mm < 2; ++mm)
                #pragma unroll
                for (int n = 0; n < 4; ++n)
                    acc[2 * p + mm][n] = __builtin_amdgcn_mfma_f32_16x16x32_bf16(
                        a[mm][kk], b[n][kk], acc[2 * p + mm][n], 0, 0, 0);
        __builtin_amdgcn_s_setprio(0);
    };

    // prologue: tile0 {B0,B1,A0,A1} + tile1 {B0,B1}; vmcnt(4) -> tile0 resident
    stB(0, 0, true); stB(0, 1, true);
    stA(0, 0, true); stA(0, 1, true);
    stB(1, 0, true); stB(1, 1, true);
    asm volatile("s_waitcnt vmcnt(4)");
    __builtin_amdgcn_s_barrier();

    for (int t = 0; t < NT; ++t) {
        const int db = t & 1;
        const char* Ah = (const char*)&lds[db][0][wr][0];
        const char* Bq = (const char*)&lds[db][1][wcH][0] + wcL * 8192;

        // ---- phase 0: 12 reads + stage A0(t+1) ----
        rdB(Bq);
        rdA(aE, Ah, 0);
        stA(db ^ 1, 0, t + 1 < NT);
        __builtin_amdgcn_sched_barrier(0);
        asm volatile("s_waitcnt lgkmcnt(8)");
        __builtin_amdgcn_s_barrier();
        asm volatile("s_waitcnt lgkmcnt(0)");
        __builtin_amdgcn_sched_barrier(0);
        mf(aE, 0);
        __builtin_amdgcn_sched_barrier(0);
        __builtin_amdgcn_s_barrier();

        // ---- phase 1: 4 reads + stage A1(t+1) ----
        rdA(aO, Ah, 1);
        stA(db ^ 1, 1, t + 1 < NT);
        __builtin_amdgcn_sched_barrier(0);
        __builtin_amdgcn_s_barrier();
        asm volatile("s_waitcnt lgkmcnt(0)");
        __builtin_amdgcn_sched_barrier(0);
        mf(aO, 1);
        __builtin_amdgcn_sched_barrier(0);
        __builtin_amdgcn_s_barrier();

        // ---- phase 2: 4 reads + stage B0(t+2) ----
        rdA(aE, Ah, 2);
        stB(db, 0, t + 2 < NT);
        __builtin_amdgcn_sched_barrier(0);
        __builtin_amdgcn_s_barrier();
        asm volatile("s_waitcnt lgkmcnt(0)");
        __builtin_amdgcn_sched_barrier(0);
        mf(aE, 2);
        __builtin_amdgcn_sched_barrier(0);
        __builtin_amdgcn_s_barrier();

        // ---- phase 3: 4 reads + stage B1(t+2) + counted vmcnt ----
        rdA(aO, Ah, 3);
        stB(db, 1, t + 2 < NT);
        __builtin_amdgcn_sched_barrier(0);
        __builtin_amdgcn_s_barrier();
        asm volatile("s_waitcnt lgkmcnt(0)");
        __builtin_amdgcn_sched_barrier(0);
        mf(aO, 3);
        __builtin_amdgcn_sched_barrier(0);
        if (t < NT - 2)       asm volatile("s_waitcnt vmcnt(4)");
        else if (t == NT - 2) asm volatile("s_waitcnt vmcnt(0)");
        __builtin_amdgcn_s_barrier();
    }

    // ---------------- coalesced epilogue via LDS re-staging ----------------
    // C/D frag layout: col = lane&15, row = (lane>>4)*4 + reg
    const float* be = bias + (size_t)e * sBias;
    if (EPI == 0) {
        // bf16 out: whole 256x256 tile as u16 -> 128 KiB, one pass
        u16* cl = (u16*)&lds[0][0][0][0];
        #pragma unroll
        for (int n = 0; n < 4; ++n) {
            const int ccol = wc * 64 + n * 16 + fr;
            const float bv = be[col0 + ccol];
            #pragma unroll
            for (int m = 0; m < 8; ++m) {
                const int crow = wr * 128 + m * 16 + fq * 4;
                #pragma unroll
                for (int i = 0; i < 4; ++i) {
                    float v = acc[m][n][i] + bv;
                    v = v > 0.f ? v : 0.f;
                    cl[(crow + i) * 256 + ccol] = f2bf(v);
                }
            }
        }
        __builtin_amdgcn_s_barrier();
        u16* Ce = (u16*)Cv + (size_t)e * sC;
        const int rr = tid >> 5;           // 0..15
        const int cc = (tid & 31) * 8;     // u16 col, 16B granular
        #pragma unroll
        for (int s = 0; s < 16; ++s) {
            const int row = s * 16 + rr;
            const float4 v = *(const float4*)&cl[row * 256 + cc];
            *(float4*)&Ce[(size_t)(row0 + row) * N + col0 + cc] = v;
        }
    } else {
        // fp32 out: two passes of 128 rows (128 KiB each)
        float* cf = (float*)&lds[0][0][0][0];
        float* Ce = (float*)Cv + (size_t)e * sC;
        #pragma unroll
        for (int p = 0; p < 2; ++p) {
            __builtin_amdgcn_s_barrier();
            #pragma unroll
            for (int n = 0; n < 4; ++n) {
                const int ccol = wc * 64 + n * 16 + fr;
                const float bv = be[col0 + ccol];
                #pragma unroll
                for (int mm = 0; mm < 4; ++mm) {
                    const int lrow = wr * 64 + mm * 16 + fq * 4;
                    #pragma unroll
                    for (int i = 0; i < 4; ++i)
                        cf[(lrow + i) * 256 + ccol] = acc[p * 4 + mm][n][i] + bv;
                }
            }
            __builtin_amdgcn_s_barrier();
            const int lr = tid >> 6;          // 0..7
            const int cc = (tid & 63) * 4;    // f32 col, 16B granular
            #pragma unroll
            for (int s = 0; s < 16; ++s) {
                const int lrow = s * 8 + lr;
                const int wrr  = lrow >> 6;
                const int rem2 = lrow & 63;
                const int grow = row0 + wrr * 128 + p * 64 + rem2;
                const float4 v = *(const float4*)&cf[lrow * 256 + cc];
                *(float4*)&Ce[(size_t)grow * N + col0 + cc] = v;
            }
        }
    }
}

extern "C" void kernel_launch(void* const* d_in, const int* in_sizes, int n_in,
                              void* d_out, int out_size, void* d_ws, size_t ws_size,
                              hipStream_t stream) {
    (void)in_sizes; (void)n_in; (void)out_size; (void)ws_size;
    const float* x     = (const float*)d_in[0];
    const float* fc1_w = (const float*)d_in[1];
    const float* fc1_b = (const float*)d_in[2];
    const float* fc2_w = (const float*)d_in[3];
    const float* fc2_b = (const float*)d_in[4];
    float* out = (float*)d_out;

    // workspace layout (ushorts): xbf | w1bf | w2t | y1  => 288 MiB total
    u16* xbf  = (u16*)d_ws;                                 // E*CAP*D
    u16* w1bf = xbf  + (size_t)E_ * CAP_ * D_;              // E*H*D
    u16* w2t  = w1bf + (size_t)E_ * H_ * D_;                // E*D*H (transposed)
    u16* y1   = w2t  + (size_t)E_ * D_ * H_;                // E*CAP*H

    {   // x -> bf16
        int n4 = E_ * CAP_ * D_ / 4;
        cvt_f32_bf16<<<n4 / 256, 256, 0, stream>>>(x, xbf, n4);
    }
    {   // W1 -> bf16
        int n4 = E_ * H_ * D_ / 4;
        cvt_f32_bf16<<<n4 / 256, 256, 0, stream>>>(fc1_w, w1bf, n4);
    }
    // W2 -> bf16 transposed [E][D][H]
    transpose_cvt<<<dim3(D_ / 64, H_ / 64, E_), 256, 0, stream>>>(fc2_w, w2t);

    // GEMM1: y1[e] = relu(x[e] @ W1[e]^T + b1)   (M=CAP, N=H, K=D)
    gemm256<0><<<dim3(E_ * (CAP_ / 256) * (H_ / 256)), 512, 0, stream>>>(
        xbf, w1bf, fc1_b, y1, CAP_, H_, D_, CAP_ / 256, H_ / 256,
        (size_t)CAP_ * D_, (size_t)H_ * D_, (size_t)H_, (size_t)CAP_ * H_);

    // GEMM2: out[e] = y1[e] @ W2T[e]^T + b2   (M=CAP, N=D, K=H)
    gemm256<1><<<dim3(E_ * (CAP_ / 256) * (D_ / 256)), 512, 0, stream>>>(
        y1, w2t, fc2_b, out, CAP_, D_, H_, CAP_ / 256, D_ / 256,
        (size_t)CAP_ * H_, (size_t)D_ * H_, (size_t)D_, (size_t)CAP_ * D_);
}